// Round 17
// baseline (197.809 us; speedup 1.0000x reference)
//
#include <hip/hip_runtime.h>

typedef _Float16 v8h __attribute__((ext_vector_type(8)));
typedef _Float16 v2h __attribute__((ext_vector_type(2)));
typedef float    v4f __attribute__((ext_vector_type(4)));
typedef unsigned int u32;

// ---------------- Kernel 1: style modulation s[b][c] = style[b]·mod_weight[c] + bias[c]
__global__ void style_kernel(const float* __restrict__ style,
                             const float* __restrict__ mw,
                             const float* __restrict__ mb,
                             float* __restrict__ s_out) {
    const int b = blockIdx.x;          // 16 blocks
    const int t = threadIdx.x;         // 256 threads
    const int c = t >> 2, q = t & 3;   // 4 threads per channel, 128 elems each
    const float* st = style + b * 512 + q * 128;
    const float* w  = mw + c * 512 + q * 128;
    float acc = 0.f;
    #pragma unroll 8
    for (int i = 0; i < 128; ++i) acc += st[i] * w[i];
    acc += __shfl_xor(acc, 1);
    acc += __shfl_xor(acc, 2);
    if (q == 0) s_out[b * 64 + c] = acc + mb[c];
}

// ---------------- Kernel 2: modulate + demodulate + repack weights into A-fragment layout
// wA layout: [b][tap][ks*4+ot][lane][j] (f16): lane l holds o = ot*16 + (l&15),
// k(channel) = ks*32 + (l>>4)*8 + j  -> mfma_f32_16x16x32 A-operand layout.
__global__ void wprep_kernel(const float* __restrict__ weight,
                             const float* __restrict__ s,
                             _Float16* __restrict__ wA) {
    const int blk = blockIdx.x;            // 1024 = B*O
    const int b = blk >> 6, o = blk & 63;
    const int lane = threadIdx.x;          // 64
    const float* wo = weight + o * 576;    // weight[0][o][c][kh][kw]
    const float* sb = s + b * 64;
    float vals[9];
    float sum = 0.f;
    #pragma unroll
    for (int k = 0; k < 9; ++k) {
        int e = lane + k * 64;             // 0..575
        int c = e / 9;
        float v = wo[e] * sb[c];
        vals[k] = v;
        sum += v * v;
    }
    #pragma unroll
    for (int off = 32; off; off >>= 1) sum += __shfl_xor(sum, off);
    const float demod = 1.f / sqrtf(sum + 1e-8f);
    #pragma unroll
    for (int k = 0; k < 9; ++k) {
        int e = lane + k * 64;
        int c = e / 9, tap = e - c * 9;
        int ks = c >> 5, lg = (c >> 3) & 3, j = c & 7;
        int dst = (((b * 9 + tap) * 8 + ks * 4 + (o >> 4)) * 64 + lg * 16 + (o & 15)) * 8 + j;
        wA[dst] = (_Float16)(vals[k] * demod);
    }
}

// ---------------- Kernel 2b: interior transpose x NCHW f32 -> padded NHWC f16.
// (r14 best-measured version.) x reads NON-TEMPORAL (keep L3 for xh). Border
// zeroing folded (tid<5). Phase-2 stores 1KB contiguous/wave-instr.
__global__ __launch_bounds__(256)
void xprep_kernel(const float* __restrict__ x, _Float16* __restrict__ xh) {
    __shared__ u32 lt[32 * 257];   // [cpair][w + pad] : 32896 B
    const int tid = threadIdx.x;
    const int h = blockIdx.x;    // 0..255
    const int b = blockIdx.y;

    const float* xr = x + ((size_t)b << 22) + (h << 8) + tid;   // w = tid
    float va[64];
    #pragma unroll
    for (int c = 0; c < 64; ++c)
        va[c] = __builtin_nontemporal_load(&xr[(size_t)c << 16]);
    #pragma unroll
    for (int cp = 0; cp < 32; ++cp) {
        union { v2h h2; u32 u; } pk;
        pk.h2[0] = (_Float16)va[2 * cp];
        pk.h2[1] = (_Float16)va[2 * cp + 1];
        lt[cp * 257 + tid] = pk.u;
    }

    if (tid < 5) {
        const int idx = blockIdx.x * 5 + tid;
        if (idx < 1028) {
            int row, col;
            if (idx < 258)        { row = 0;             col = idx; }
            else if (idx < 516)   { row = 257;           col = idx - 258; }
            else if (idx < 772)   { row = idx - 516 + 1; col = 0; }
            else                  { row = idx - 772 + 1; col = 257; }
            v8h z = {};
            _Float16* p = xh + (size_t)b * (258 * 258 * 64)
                             + (size_t)(row * 258 + col) * 64;
            #pragma unroll
            for (int g = 0; g < 8; ++g)
                *reinterpret_cast<v8h*>(p + g * 8) = z;
        }
    }
    __syncthreads();

    _Float16* rowb = xh + ((size_t)(b * 258 + h + 1) * 258 + 1) * 64;
    #pragma unroll
    for (int k = 0; k < 8; ++k) {
        const int G = (k << 8) + tid;     // granule id: pix*8 + g
        const int pix = G >> 3, g = G & 7;
        union { u32 u[4]; v8h h8; } as_;
        #pragma unroll
        for (int jj = 0; jj < 4; ++jj)
            as_.u[jj] = lt[(4 * g + jj) * 257 + pix];
        *reinterpret_cast<v8h*>(rowb + (size_t)G * 8) = as_.h8;
    }
}

// ---------------- Kernel 3: implicit-GEMM conv, 32x16 tile, 12-row LDS RING
// -> LDS 52224 B -> 3 blocks/CU (was 2). Slot = row mod 12; 12*34=408 ≡ 0 mod 8
// so the XOR swizzle (pix&7) is identical in slot- and global-space.
// Schedule: stage rows0-11 | vmcnt(3)+bar | pair0 (rows<=9) | bar |
// stage rows12-17 -> slots0-5 | vmcnt(0)+bar | NT-store p0 | pair1 | NT-store p1.
__global__ __launch_bounds__(256, 3)
void conv_kernel(const _Float16* __restrict__ xh,
                 const _Float16* __restrict__ wA,
                 float* __restrict__ out) {
    __shared__ __align__(16) _Float16 lds[408 * 64];   // 52224 B (12 rows x 34 px)

    const int tid = threadIdx.x;
    const int fid = blockIdx.x + (blockIdx.y << 3) + (blockIdx.z << 7);
    const int vid = ((fid & 7) << 8) + (fid >> 3);
    const int tx = vid & 7;          // w-tile (32 wide)
    const int ty = (vid >> 3) & 15;  // h-tile (16 high)
    const int b  = vid >> 7;

    const int h0 = ty << 4;
    const int w0 = tx << 5;

    const int lane = tid & 63, wv = tid >> 6;
    const _Float16* xhb = xh + (size_t)b * (258 * 258 * 64);

    // stage(Ag -> dest granule Ad): source swizzled by global pix&7
    auto stage = [&](int Ag, int Ad) {
        const int pix = Ag >> 3, g = Ag & 7;
        const int ph = pix / 34, pw = pix - ph * 34;
        const _Float16* src = xhb + (size_t)((h0 + ph) * 258 + (w0 + pw)) * 64
                                  + ((g ^ (pix & 7)) << 3);
        __builtin_amdgcn_global_load_lds(
            (const __attribute__((address_space(1))) void*)src,
            (__attribute__((address_space(3))) void*)(lds + (size_t)Ad * 8),
            16, 0, 0);
    };

    // chunk0: rows 0..9 (granules 0..2719), 11 instrs/wave
    #pragma unroll
    for (int i = 0; i < 11; ++i) {
        const int k = wv + (i << 2);                 // 0..43
        const int g0 = min(k << 6, 2656);
        stage(g0 + lane, g0 + lane);
    }
    // chunk1: rows 10,11 (granules 2720..3263), 3 instrs/wave
    #pragma unroll
    for (int i = 0; i < 3; ++i) {
        const int k = wv + (i << 2);                 // 0..11
        const int g0 = 2720 + min(k << 6, 480);
        stage(g0 + lane, g0 + lane);
    }

    const int n = lane & 15, lg = lane >> 4;
    const _Float16* wab = wA + (size_t)b * (9 * 8 * 64 * 8);

    v4f acc[4][2][2];   // [ot][hf][rq]

    // chunk0 done (3 chunk1 instrs stay in flight)
    asm volatile("s_waitcnt vmcnt(3)" ::: "memory");
    __builtin_amdgcn_s_barrier();
    __builtin_amdgcn_sched_barrier(0);

    // ---- pair 0: out rows wv, wv+4 (halo rows <= 9; slot == row)
    #pragma unroll
    for (int ot = 0; ot < 4; ++ot)
        #pragma unroll
        for (int hf = 0; hf < 2; ++hf)
            #pragma unroll
            for (int rq = 0; rq < 2; ++rq)
                acc[ot][hf][rq] = (v4f)0.f;

    #pragma unroll
    for (int t = 0; t < 9; ++t) {
        const int dh = t / 3, dw = t - dh * 3;
        v8h a[4][2];
        #pragma unroll
        for (int ot = 0; ot < 4; ++ot)
            #pragma unroll
            for (int ks = 0; ks < 2; ++ks)
                a[ot][ks] = *reinterpret_cast<const v8h*>(
                    wab + ((size_t)((t * 8 + ks * 4 + ot) * 64 + lane)) * 8);
        #pragma unroll
        for (int rq = 0; rq < 2; ++rq) {
            const int R = wv + (rq << 2);
            #pragma unroll
            for (int hf = 0; hf < 2; ++hf) {
                const int pix = (R + dh) * 34 + n + (hf << 4) + dw;
                const char* pb = reinterpret_cast<const char*>(lds) + pix * 128;
                const int px7 = pix & 7;
                #pragma unroll
                for (int ks = 0; ks < 2; ++ks) {
                    v8h bf = *reinterpret_cast<const v8h*>(
                        pb + ((((ks << 2) + lg) ^ px7) << 4));
                    #pragma unroll
                    for (int ot = 0; ot < 4; ++ot)
                        acc[ot][hf][rq] = __builtin_amdgcn_mfma_f32_16x16x32_f16(
                            a[ot][ks], bf, acc[ot][hf][rq], 0, 0, 0);
                }
            }
        }
    }

    // all waves done reading slots 0..5 -> safe to overwrite
    __builtin_amdgcn_s_barrier();
    __builtin_amdgcn_sched_barrier(0);

    // chunk2: rows 12..17 -> slots 0..5 (src granules 3264..4895), 7 instrs/wave
    #pragma unroll
    for (int i = 0; i < 7; ++i) {
        const int k = wv + (i << 2);                 // 0..27
        const int g0 = min(k << 6, 1568);
        stage(3264 + g0 + lane, g0 + lane);
    }
    asm volatile("s_waitcnt vmcnt(0)" ::: "memory");
    __builtin_amdgcn_s_barrier();
    __builtin_amdgcn_sched_barrier(0);

    // NT-store pair 0
    #pragma unroll
    for (int ot = 0; ot < 4; ++ot) {
        #pragma unroll
        for (int rq = 0; rq < 2; ++rq) {
            const int h = h0 + wv + (rq << 2);
            #pragma unroll
            for (int reg = 0; reg < 4; ++reg) {
                const int o = (ot << 4) + (lg << 2) + reg;
                float* op = out + (((size_t)(b * 64 + o)) << 16) + (h << 8) + w0 + n;
                __builtin_nontemporal_store(acc[ot][0][rq][reg], op);
                __builtin_nontemporal_store(acc[ot][1][rq][reg], op + 16);
            }
        }
    }

    // ---- pair 1: out rows wv+8, wv+12 (halo rows 8..17; slot = row mod 12)
    #pragma unroll
    for (int ot = 0; ot < 4; ++ot)
        #pragma unroll
        for (int hf = 0; hf < 2; ++hf)
            #pragma unroll
            for (int rq = 0; rq < 2; ++rq)
                acc[ot][hf][rq] = (v4f)0.f;

    #pragma unroll
    for (int t = 0; t < 9; ++t) {
        const int dh = t / 3, dw = t - dh * 3;
        v8h a[4][2];
        #pragma unroll
        for (int ot = 0; ot < 4; ++ot)
            #pragma unroll
            for (int ks = 0; ks < 2; ++ks)
                a[ot][ks] = *reinterpret_cast<const v8h*>(
                    wab + ((size_t)((t * 8 + ks * 4 + ot) * 64 + lane)) * 8);
        #pragma unroll
        for (int rq = 0; rq < 2; ++rq) {
            const int row = wv + 8 + (rq << 2) + dh;        // 8..17
            const int srow = (row < 12) ? row : row - 12;   // ring slot
            #pragma unroll
            for (int hf = 0; hf < 2; ++hf) {
                const int pixs = srow * 34 + n + (hf << 4) + dw;
                const char* pb = reinterpret_cast<const char*>(lds) + pixs * 128;
                const int px7 = pixs & 7;   // == global pix&7 (408 ≡ 0 mod 8)
                #pragma unroll
                for (int ks = 0; ks < 2; ++ks) {
                    v8h bf = *reinterpret_cast<const v8h*>(
                        pb + ((((ks << 2) + lg) ^ px7) << 4));
                    #pragma unroll
                    for (int ot = 0; ot < 4; ++ot)
                        acc[ot][hf][rq] = __builtin_amdgcn_mfma_f32_16x16x32_f16(
                            a[ot][ks], bf, acc[ot][hf][rq], 0, 0, 0);
                }
            }
        }
    }

    // NT-store pair 1
    #pragma unroll
    for (int ot = 0; ot < 4; ++ot) {
        #pragma unroll
        for (int rq = 0; rq < 2; ++rq) {
            const int h = h0 + wv + 8 + (rq << 2);
            #pragma unroll
            for (int reg = 0; reg < 4; ++reg) {
                const int o = (ot << 4) + (lg << 2) + reg;
                float* op = out + (((size_t)(b * 64 + o)) << 16) + (h << 8) + w0 + n;
                __builtin_nontemporal_store(acc[ot][0][rq][reg], op);
                __builtin_nontemporal_store(acc[ot][1][rq][reg], op + 16);
            }
        }
    }
}

extern "C" void kernel_launch(void* const* d_in, const int* in_sizes, int n_in,
                              void* d_out, int out_size, void* d_ws, size_t ws_size,
                              hipStream_t stream) {
    const float* x      = (const float*)d_in[0];
    const float* style  = (const float*)d_in[1];
    const float* mw     = (const float*)d_in[2];
    const float* mb     = (const float*)d_in[3];
    const float* weight = (const float*)d_in[4];
    float* out = (float*)d_out;

    float*    s_ws = (float*)d_ws;                       // 1 KB used
    _Float16* wA   = (_Float16*)((char*)d_ws + 4096);    // 1.18 MB
    _Float16* xh   = (_Float16*)((char*)d_ws + 2u * 1024u * 1024u);  // 136.3 MB

    style_kernel<<<16, 256, 0, stream>>>(style, mw, mb, s_ws);
    wprep_kernel<<<1024, 64, 0, stream>>>(weight, s_ws, wA);
    xprep_kernel<<<dim3(256, 16), 256, 0, stream>>>(x, xh);
    conv_kernel<<<dim3(8, 16, 16), 256, 0, stream>>>(xh, wA, out);
}

// Round 18
// 188.765 us; speedup vs baseline: 1.0479x; 1.0479x over previous
//
#include <hip/hip_runtime.h>

typedef _Float16 v8h __attribute__((ext_vector_type(8)));
typedef _Float16 v2h __attribute__((ext_vector_type(2)));
typedef float    v4f __attribute__((ext_vector_type(4)));
typedef unsigned int u32;

// ---------------- Kernel 1: style modulation s[b][c] = style[b]·mod_weight[c] + bias[c]
__global__ void style_kernel(const float* __restrict__ style,
                             const float* __restrict__ mw,
                             const float* __restrict__ mb,
                             float* __restrict__ s_out) {
    const int b = blockIdx.x;          // 16 blocks
    const int t = threadIdx.x;         // 256 threads
    const int c = t >> 2, q = t & 3;   // 4 threads per channel, 128 elems each
    const float* st = style + b * 512 + q * 128;
    const float* w  = mw + c * 512 + q * 128;
    float acc = 0.f;
    #pragma unroll 8
    for (int i = 0; i < 128; ++i) acc += st[i] * w[i];
    acc += __shfl_xor(acc, 1);
    acc += __shfl_xor(acc, 2);
    if (q == 0) s_out[b * 64 + c] = acc + mb[c];
}

// ---------------- Kernel 2: modulate + demodulate + repack weights into A-fragment layout
// wA layout: [b][tap][ks*4+ot][lane][j] (f16): lane l holds o = ot*16 + (l&15),
// k(channel) = ks*32 + (l>>4)*8 + j  -> mfma_f32_16x16x32 A-operand layout.
__global__ void wprep_kernel(const float* __restrict__ weight,
                             const float* __restrict__ s,
                             _Float16* __restrict__ wA) {
    const int blk = blockIdx.x;            // 1024 = B*O
    const int b = blk >> 6, o = blk & 63;
    const int lane = threadIdx.x;          // 64
    const float* wo = weight + o * 576;    // weight[0][o][c][kh][kw]
    const float* sb = s + b * 64;
    float vals[9];
    float sum = 0.f;
    #pragma unroll
    for (int k = 0; k < 9; ++k) {
        int e = lane + k * 64;             // 0..575
        int c = e / 9;
        float v = wo[e] * sb[c];
        vals[k] = v;
        sum += v * v;
    }
    #pragma unroll
    for (int off = 32; off; off >>= 1) sum += __shfl_xor(sum, off);
    const float demod = 1.f / sqrtf(sum + 1e-8f);
    #pragma unroll
    for (int k = 0; k < 9; ++k) {
        int e = lane + k * 64;
        int c = e / 9, tap = e - c * 9;
        int ks = c >> 5, lg = (c >> 3) & 3, j = c & 7;
        int dst = (((b * 9 + tap) * 8 + ks * 4 + (o >> 4)) * 64 + lg * 16 + (o & 15)) * 8 + j;
        wA[dst] = (_Float16)(vals[k] * demod);
    }
}

// ---------------- Kernel 2b: interior transpose x NCHW f32 -> padded NHWC f16.
// x reads NON-TEMPORAL (read-once stream; keep L3 for xh). Border zeroing
// folded in (tid<5 path). Phase 2 stores 1KB contiguous per wave-instr
// (full 128B lines, no RMW).
__global__ __launch_bounds__(256)
void xprep_kernel(const float* __restrict__ x, _Float16* __restrict__ xh) {
    __shared__ u32 lt[32 * 257];   // [cpair][w + pad] : 32896 B
    const int tid = threadIdx.x;
    const int h = blockIdx.x;    // 0..255
    const int b = blockIdx.y;

    const float* xr = x + ((size_t)b << 22) + (h << 8) + tid;   // w = tid
    float va[64];
    #pragma unroll
    for (int c = 0; c < 64; ++c)
        va[c] = __builtin_nontemporal_load(&xr[(size_t)c << 16]);
    #pragma unroll
    for (int cp = 0; cp < 32; ++cp) {
        union { v2h h2; u32 u; } pk;
        pk.h2[0] = (_Float16)va[2 * cp];
        pk.h2[1] = (_Float16)va[2 * cp + 1];
        lt[cp * 257 + tid] = pk.u;
    }

    // folded border zeroing: 1028 border pixel-lines per batch over 256 blocks
    if (tid < 5) {
        const int idx = blockIdx.x * 5 + tid;
        if (idx < 1028) {
            int row, col;
            if (idx < 258)        { row = 0;             col = idx; }
            else if (idx < 516)   { row = 257;           col = idx - 258; }
            else if (idx < 772)   { row = idx - 516 + 1; col = 0; }
            else                  { row = idx - 772 + 1; col = 257; }
            v8h z = {};
            _Float16* p = xh + (size_t)b * (258 * 258 * 64)
                             + (size_t)(row * 258 + col) * 64;
            #pragma unroll
            for (int g = 0; g < 8; ++g)
                *reinterpret_cast<v8h*>(p + g * 8) = z;
        }
    }
    __syncthreads();

    // pixel row base in xh (f16 units): interior pixel (h+1, w=1..256)
    _Float16* rowb = xh + ((size_t)(b * 258 + h + 1) * 258 + 1) * 64;
    #pragma unroll
    for (int k = 0; k < 8; ++k) {
        const int G = (k << 8) + tid;     // granule id: pix*8 + g
        const int pix = G >> 3, g = G & 7;
        union { u32 u[4]; v8h h8; } as_;
        #pragma unroll
        for (int jj = 0; jj < 4; ++jj)
            as_.u[jj] = lt[(4 * g + jj) * 257 + pix];
        *reinterpret_cast<v8h*>(rowb + (size_t)G * 8) = as_.h8;
    }
}

// ---------------- Kernel 3: implicit-GEMM conv, 32x16 tile, 2-chunk pipelined staging
// (global_load_lds staging, counted vmcnt, NT out stores)
__global__ __launch_bounds__(256, 2)
void conv_kernel(const _Float16* __restrict__ xh,
                 const _Float16* __restrict__ wA,
                 float* __restrict__ out) {
    __shared__ __align__(16) _Float16 lds[612 * 64];   // 78336 B

    const int tid = threadIdx.x;
    const int fid = blockIdx.x + (blockIdx.y << 3) + (blockIdx.z << 7);
    const int vid = ((fid & 7) << 8) + (fid >> 3);
    const int tx = vid & 7;          // w-tile (32 wide)
    const int ty = (vid >> 3) & 15;  // h-tile (16 high)
    const int b  = vid >> 7;

    const int h0 = ty << 4;
    const int w0 = tx << 5;

    const int lane = tid & 63, wv = tid >> 6;
    const _Float16* xhb = xh + (size_t)b * (258 * 258 * 64);

    #pragma unroll
    for (int i = 0; i < 11; ++i) {
        const int k = wv + (i << 2);
        const int g0 = (k < 43) ? ((k << 6) < 2656 ? (k << 6) : 2656) : 0;
        const int A = g0 + lane;
        const int pix = A >> 3, g = A & 7;
        const int ph = pix / 34, pw = pix - ph * 34;
        const _Float16* src = xhb + (size_t)((h0 + ph) * 258 + (w0 + pw)) * 64
                                  + ((g ^ (pix & 7)) << 3);
        __builtin_amdgcn_global_load_lds(
            (const __attribute__((address_space(1))) void*)src,
            (__attribute__((address_space(3))) void*)(lds + (size_t)A * 8),
            16, 0, 0);
    }
    #pragma unroll
    for (int i = 0; i < 9; ++i) {
        const int k = wv + (i << 2);
        const int g0 = 2720 + ((k < 34) ? (k << 6) : 0);
        const int A = g0 + lane;
        const int pix = A >> 3, g = A & 7;
        const int ph = pix / 34, pw = pix - ph * 34;
        const _Float16* src = xhb + (size_t)((h0 + ph) * 258 + (w0 + pw)) * 64
                                  + ((g ^ (pix & 7)) << 3);
        __builtin_amdgcn_global_load_lds(
            (const __attribute__((address_space(1))) void*)src,
            (__attribute__((address_space(3))) void*)(lds + (size_t)A * 8),
            16, 0, 0);
    }

    const int n = lane & 15, lg = lane >> 4;
    const _Float16* wab = wA + (size_t)b * (9 * 8 * 64 * 8);

    v4f acc[4][2][2];   // [ot][hf][rq]

    asm volatile("s_waitcnt vmcnt(9)" ::: "memory");
    __builtin_amdgcn_s_barrier();
    __builtin_amdgcn_sched_barrier(0);

    // ---- pair 0: out rows wv, wv+4 (halo rows <= 9)
    #pragma unroll
    for (int ot = 0; ot < 4; ++ot)
        #pragma unroll
        for (int hf = 0; hf < 2; ++hf)
            #pragma unroll
            for (int rq = 0; rq < 2; ++rq)
                acc[ot][hf][rq] = (v4f)0.f;

    #pragma unroll
    for (int t = 0; t < 9; ++t) {
        const int dh = t / 3, dw = t - dh * 3;
        v8h a[4][2];
        #pragma unroll
        for (int ot = 0; ot < 4; ++ot)
            #pragma unroll
            for (int ks = 0; ks < 2; ++ks)
                a[ot][ks] = *reinterpret_cast<const v8h*>(
                    wab + ((size_t)((t * 8 + ks * 4 + ot) * 64 + lane)) * 8);
        #pragma unroll
        for (int rq = 0; rq < 2; ++rq) {
            const int R = wv + (rq << 2);
            #pragma unroll
            for (int hf = 0; hf < 2; ++hf) {
                const int pix = (R + dh) * 34 + n + (hf << 4) + dw;
                const char* pb = reinterpret_cast<const char*>(lds) + pix * 128;
                const int px7 = pix & 7;
                #pragma unroll
                for (int ks = 0; ks < 2; ++ks) {
                    v8h bf = *reinterpret_cast<const v8h*>(
                        pb + ((((ks << 2) + lg) ^ px7) << 4));
                    #pragma unroll
                    for (int ot = 0; ot < 4; ++ot)
                        acc[ot][hf][rq] = __builtin_amdgcn_mfma_f32_16x16x32_f16(
                            a[ot][ks], bf, acc[ot][hf][rq], 0, 0, 0);
                }
            }
        }
    }

    asm volatile("s_waitcnt vmcnt(0)" ::: "memory");
    __builtin_amdgcn_s_barrier();
    __builtin_amdgcn_sched_barrier(0);

    #pragma unroll
    for (int ot = 0; ot < 4; ++ot) {
        #pragma unroll
        for (int rq = 0; rq < 2; ++rq) {
            const int h = h0 + wv + (rq << 2);
            #pragma unroll
            for (int reg = 0; reg < 4; ++reg) {
                const int o = (ot << 4) + (lg << 2) + reg;
                float* op = out + (((size_t)(b * 64 + o)) << 16) + (h << 8) + w0 + n;
                __builtin_nontemporal_store(acc[ot][0][rq][reg], op);
                __builtin_nontemporal_store(acc[ot][1][rq][reg], op + 16);
            }
        }
    }

    // ---- pair 1: out rows wv+8, wv+12 (halo rows 8..17)
    #pragma unroll
    for (int ot = 0; ot < 4; ++ot)
        #pragma unroll
        for (int hf = 0; hf < 2; ++hf)
            #pragma unroll
            for (int rq = 0; rq < 2; ++rq)
                acc[ot][hf][rq] = (v4f)0.f;

    #pragma unroll
    for (int t = 0; t < 9; ++t) {
        const int dh = t / 3, dw = t - dh * 3;
        v8h a[4][2];
        #pragma unroll
        for (int ot = 0; ot < 4; ++ot)
            #pragma unroll
            for (int ks = 0; ks < 2; ++ks)
                a[ot][ks] = *reinterpret_cast<const v8h*>(
                    wab + ((size_t)((t * 8 + ks * 4 + ot) * 64 + lane)) * 8);
        #pragma unroll
        for (int rq = 0; rq < 2; ++rq) {
            const int R = wv + 8 + (rq << 2);
            #pragma unroll
            for (int hf = 0; hf < 2; ++hf) {
                const int pix = (R + dh) * 34 + n + (hf << 4) + dw;
                const char* pb = reinterpret_cast<const char*>(lds) + pix * 128;
                const int px7 = pix & 7;
                #pragma unroll
                for (int ks = 0; ks < 2; ++ks) {
                    v8h bf = *reinterpret_cast<const v8h*>(
                        pb + ((((ks << 2) + lg) ^ px7) << 4));
                    #pragma unroll
                    for (int ot = 0; ot < 4; ++ot)
                        acc[ot][hf][rq] = __builtin_amdgcn_mfma_f32_16x16x32_f16(
                            a[ot][ks], bf, acc[ot][hf][rq], 0, 0, 0);
                }
            }
        }
    }

    #pragma unroll
    for (int ot = 0; ot < 4; ++ot) {
        #pragma unroll
        for (int rq = 0; rq < 2; ++rq) {
            const int h = h0 + wv + 8 + (rq << 2);
            #pragma unroll
            for (int reg = 0; reg < 4; ++reg) {
                const int o = (ot << 4) + (lg << 2) + reg;
                float* op = out + (((size_t)(b * 64 + o)) << 16) + (h << 8) + w0 + n;
                __builtin_nontemporal_store(acc[ot][0][rq][reg], op);
                __builtin_nontemporal_store(acc[ot][1][rq][reg], op + 16);
            }
        }
    }
}

extern "C" void kernel_launch(void* const* d_in, const int* in_sizes, int n_in,
                              void* d_out, int out_size, void* d_ws, size_t ws_size,
                              hipStream_t stream) {
    const float* x      = (const float*)d_in[0];
    const float* style  = (const float*)d_in[1];
    const float* mw     = (const float*)d_in[2];
    const float* mb     = (const float*)d_in[3];
    const float* weight = (const float*)d_in[4];
    float* out = (float*)d_out;

    float*    s_ws = (float*)d_ws;                       // 1 KB used
    _Float16* wA   = (_Float16*)((char*)d_ws + 4096);    // 1.18 MB
    _Float16* xh   = (_Float16*)((char*)d_ws + 2u * 1024u * 1024u);  // 136.3 MB

    style_kernel<<<16, 256, 0, stream>>>(style, mw, mb, s_ws);
    wprep_kernel<<<1024, 64, 0, stream>>>(weight, s_ws, wA);
    xprep_kernel<<<dim3(256, 16), 256, 0, stream>>>(x, xh);
    conv_kernel<<<dim3(8, 16, 16), 256, 0, stream>>>(xh, wA, out);
}